// Round 1
// baseline (84.118 us; speedup 1.0000x reference)
//
#include <hip/hip_runtime.h>

#define CH   512
#define BATCH 16
#define HW   3136      // 56*56
#define HW4  784       // HW/4 (float4 per image plane)
#define THRESH 8.0f

// ---- Kernel 1: per-channel max|x| over (B,H,W) --------------------------
__global__ __launch_bounds__(256) void absmax_kernel(const float* __restrict__ x,
                                                     float* __restrict__ maxv) {
    const int c   = blockIdx.x;       // channel
    const int tid = threadIdx.x;
    const float4* x4 = reinterpret_cast<const float4*>(x);
    float m = 0.0f;
    // iterate over B*HW4 float4 chunks of this channel
    for (int idx = tid; idx < BATCH * HW4; idx += 256) {
        int bb = idx / HW4;
        int p  = idx - bb * HW4;
        float4 v = x4[(size_t)(bb * CH + c) * HW4 + p];
        m = fmaxf(m, fmaxf(fmaxf(fabsf(v.x), fabsf(v.y)),
                           fmaxf(fabsf(v.z), fabsf(v.w))));
    }
    __shared__ float sm[256];
    sm[tid] = m;
    __syncthreads();
    for (int off = 128; off > 0; off >>= 1) {
        if (tid < off) sm[tid] = fmaxf(sm[tid], sm[tid + off]);
        __syncthreads();
    }
    if (tid == 0) maxv[c] = sm[0];
}

// ---- Kernel 2: build plan (rep idx, 1/T scales, outlier list) -----------
__global__ __launch_bounds__(CH) void plan_kernel(const float* __restrict__ maxv,
                                                  int*   __restrict__ rep,
                                                  float* __restrict__ invT,
                                                  float* __restrict__ out_tail) {
    const int t = threadIdx.x;        // one thread per channel (512)
    float m = maxv[t];
    int T = 0;
    if (m > THRESH) T = (int)ceilf(m * 0.125f);   // ceil(m/8), /8 exact
    int isout = (T > 0) ? 1 : 0;

    __shared__ int sT[CH];
    __shared__ int sO[CH];
    sT[t] = T;
    sO[t] = isout;
    __syncthreads();
    // Hillis-Steele inclusive scan (read phase / sync / write phase / sync)
    for (int off = 1; off < CH; off <<= 1) {
        int a = 0, b = 0;
        if (t >= off) { a = sT[t - off]; b = sO[t - off]; }
        __syncthreads();
        sT[t] += a;
        sO[t] += b;
        __syncthreads();
    }
    if (T > 0) {
        int s = sT[t] - T;      // exclusive prefix of T -> start slot in rep
        int o = sO[t] - isout;  // exclusive prefix of outlier flag
        out_tail[o] = (float)t; // outlier channel id, as fp32 (flat fp32 d_out)
        float iv = (float)(1.0 / (double)T);   // match numpy f64->f32 exactly
        for (int k = 0; k < T; ++k) {
            rep[s + k]  = t;
            invT[s + k] = iv;
        }
    }
}

// ---- Kernel 3: gather + scale  out[b,j,:,:] = x[b,rep[j],:,:] * invT[j] -
__global__ __launch_bounds__(256) void gather_kernel(const float* __restrict__ x,
                                                     const int*   __restrict__ rep,
                                                     const float* __restrict__ invT,
                                                     float* __restrict__ out,
                                                     int R) {
    const int j = blockIdx.x;   // output channel
    const int b = blockIdx.y;   // batch
    const int c = rep[j];       // uniform per block -> scalar broadcast
    const float s = invT[j];
    const float4* src = reinterpret_cast<const float4*>(x)
                        + (size_t)(b * CH + c) * HW4;
    float4* dst = reinterpret_cast<float4*>(out)
                  + ((size_t)b * R + j) * HW4;
    for (int p = threadIdx.x; p < HW4; p += 256) {
        float4 v = src[p];
        v.x *= s; v.y *= s; v.z *= s; v.w *= s;
        dst[p] = v;
    }
}

extern "C" void kernel_launch(void* const* d_in, const int* in_sizes, int n_in,
                              void* d_out, int out_size, void* d_ws, size_t ws_size,
                              hipStream_t stream) {
    const float* x = (const float*)d_in[0];
    float* out = (float*)d_out;

    // out_size = 50176*R + n_out,  n_out <= 512 < 50176  -> unique split
    const int plane = BATCH * HW;               // 50176
    const int R     = out_size / plane;         // replicated channel count
    // workspace layout: [CH floats maxv][R ints rep][R floats invT]
    float* maxv = (float*)d_ws;
    int*   rep  = (int*)((char*)d_ws + CH * sizeof(float));
    float* invT = (float*)((char*)d_ws + CH * sizeof(float) + (size_t)R * sizeof(int));

    absmax_kernel<<<CH, 256, 0, stream>>>(x, maxv);
    plan_kernel<<<1, CH, 0, stream>>>(maxv, rep, invT, out + (size_t)R * plane);
    if (R > 0) {
        gather_kernel<<<dim3(R, BATCH), 256, 0, stream>>>(x, rep, invT, out, R);
    }
}